// Round 1
// baseline (195.653 us; speedup 1.0000x reference)
//
#include <hip/hip_runtime.h>
#include <limits.h>
#include <math.h>

// HICS strategy: per-entity top-k incident-edge sampling + relation-embedding mean.
// Round 1: correctness-first. One block per batch entity; full edge scan per block.
// Working set (src+dst = 2 MB) is L2-resident per XCD, so the 512x re-read is
// served from L2 (~35 TB/s aggregate) -> ~30 us floor.

#define MAX_CAND 1024   // per-direction candidate cap; expected count ~13 (Poisson), cap is ~75 sigma
#define MAXK     16     // k=10 <= 16

__global__ __launch_bounds__(256) void hics_kernel(
    const int*   __restrict__ entity_index,
    const int*   __restrict__ edge_src,
    const int*   __restrict__ edge_dst,
    const int*   __restrict__ edge_types,
    const float* __restrict__ edge_times,
    const float* __restrict__ qw,
    const int*   __restrict__ k_ptr,
    float*       __restrict__ out,
    int E, int D)
{
    const int b    = blockIdx.x;
    const int tid  = threadIdx.x;
    const int nthr = blockDim.x;

    const int e  = entity_index[b];
    const int k  = k_ptr[0];
    const int kh = k >> 1;

    __shared__ int   s_inc_n;
    __shared__ int   s_out_n;
    __shared__ float inc_t[MAX_CAND];
    __shared__ int   inc_ty[MAX_CAND];
    __shared__ int   inc_ix[MAX_CAND];
    __shared__ float out_t[MAX_CAND];
    __shared__ int   out_ty[MAX_CAND];
    __shared__ int   out_ix[MAX_CAND];
    __shared__ int   sel_ty[2 * MAXK];

    if (tid == 0) { s_inc_n = 0; s_out_n = 0; }
    __syncthreads();

    // ---- Phase 1: scan all edges, collect matches into LDS ----
    const int  nvec = E >> 2;
    const int4* src4 = (const int4*)edge_src;
    const int4* dst4 = (const int4*)edge_dst;
    for (int v = tid; v < nvec; v += nthr) {
        const int4 s4 = src4[v];
        const int4 d4 = dst4[v];
        const int base = v << 2;
        const int ss[4] = { s4.x, s4.y, s4.z, s4.w };
        const int dd[4] = { d4.x, d4.y, d4.z, d4.w };
        #pragma unroll
        for (int j = 0; j < 4; ++j) {
            if (dd[j] == e) {
                int p = atomicAdd(&s_inc_n, 1);
                if (p < MAX_CAND) {
                    int i = base + j;
                    inc_t[p]  = edge_times[i];
                    inc_ty[p] = edge_types[i];
                    inc_ix[p] = i;
                }
            }
            if (ss[j] == e) {
                int p = atomicAdd(&s_out_n, 1);
                if (p < MAX_CAND) {
                    int i = base + j;
                    out_t[p]  = edge_times[i];
                    out_ty[p] = edge_types[i];
                    out_ix[p] = i;
                }
            }
        }
    }
    // tail (E not divisible by 4)
    for (int i = (nvec << 2) + tid; i < E; i += nthr) {
        if (edge_dst[i] == e) {
            int p = atomicAdd(&s_inc_n, 1);
            if (p < MAX_CAND) { inc_t[p] = edge_times[i]; inc_ty[p] = edge_types[i]; inc_ix[p] = i; }
        }
        if (edge_src[i] == e) {
            int p = atomicAdd(&s_out_n, 1);
            if (p < MAX_CAND) { out_t[p] = edge_times[i]; out_ty[p] = edge_types[i]; out_ix[p] = i; }
        }
    }
    __syncthreads();

    const int inc_count_full = s_inc_n;
    const int out_count_full = s_out_n;
    const int inc_count = min(inc_count_full, MAX_CAND);
    const int out_count = min(out_count_full, MAX_CAND);

    const int inc_take  = min(kh, inc_count_full);
    const int remaining = (inc_take > 0) ? (k - inc_take) : k;
    const int out_take  = min(remaining, out_count_full);

    // ---- Phase 2: rank-based parallel top-k selection ----
    // Total order: time desc, edge-index asc (matches lax.top_k tie-breaking).
    const int half = nthr >> 1;
    if (tid < half) {
        for (int j = tid; j < inc_count; j += half) {
            const float tj = inc_t[j];
            const int   ij = inc_ix[j];
            int rank = 0;
            for (int m = 0; m < inc_count; ++m) {
                const float tm = inc_t[m];
                const int   im = inc_ix[m];
                if (tm > tj || (tm == tj && im < ij)) rank++;
            }
            if (rank < inc_take) sel_ty[rank] = inc_ty[j];
        }
    } else {
        for (int j = tid - half; j < out_count; j += half) {
            const float tj = out_t[j];
            const int   ij = out_ix[j];
            int rank = 0;
            for (int m = 0; m < out_count; ++m) {
                const float tm = out_t[m];
                const int   im = out_ix[m];
                if (tm > tj || (tm == tj && im < ij)) rank++;
            }
            if (rank < out_take) sel_ty[MAXK + rank] = out_ty[j];
        }
    }
    __syncthreads();

    // ---- Phase 3: masked-mean aggregate over selected relation embeddings ----
    const int cnt = inc_take + out_take;
    const float inv = 1.0f / (float)max(cnt, 1);
    for (int d = tid; d < D; d += nthr) {
        float acc = 0.0f;
        for (int s = 0; s < inc_take; ++s) acc += qw[sel_ty[s] * D + d];
        for (int s = 0; s < out_take; ++s) acc += qw[sel_ty[MAXK + s] * D + d];
        out[(size_t)b * D + d] = acc * inv;
    }
}

extern "C" void kernel_launch(void* const* d_in, const int* in_sizes, int n_in,
                              void* d_out, int out_size, void* d_ws, size_t ws_size,
                              hipStream_t stream)
{
    const int*   entity_index = (const int*)d_in[0];
    const int*   edge_src     = (const int*)d_in[1];
    const int*   edge_dst     = (const int*)d_in[2];
    const int*   edge_types   = (const int*)d_in[3];
    const float* edge_times   = (const float*)d_in[4];
    const float* qw           = (const float*)d_in[5];
    const int*   k_ptr        = (const int*)d_in[6];
    float*       out          = (float*)d_out;

    const int B = in_sizes[0];
    const int E = in_sizes[1];
    const int D = out_size / B;

    hipLaunchKernelGGL(hics_kernel, dim3(B), dim3(256), 0, stream,
                       entity_index, edge_src, edge_dst, edge_types, edge_times, qw,
                       k_ptr, out, E, D);
}

// Round 2
// 85.734 us; speedup vs baseline: 2.2821x; 2.2821x over previous
//
#include <hip/hip_runtime.h>
#include <limits.h>
#include <math.h>

// HICS strategy, round 2: edge-centric inversion.
// R1 was O(B*E) brute force: 512 blocks x 2MB L2-resident scan = 1 GB of L2
// traffic, latency-bound at ~160us (occupancy capped at 2 blocks/CU).
// R2: build node->batch chained hash (exact, array-indexed), scan edges ONCE,
// push matches (~26 per batch entry) into per-batch candidate lists, then
// rank-select top-k and aggregate. O(E) total memory touch (~5 MB).
//
// Selection key packs (time desc, edge_idx asc) exactly matching lax.top_k
// ordering: key = (float_bits(time) << 32) | (0xFFFFFFFF - edge_idx).
// edge_times are uniform [0,1) -> nonneg floats -> bit pattern is monotonic.

#define CAP  256   // per-direction candidate cap; per-node degree ~ Binom(E,1/N), mean 13.1, CAP=256 is >60 sigma
#define MAXK 16    // k=10 <= 16

// ---- Kernel A0: init table and counts ----
__global__ void init_kernel(int* __restrict__ table, int* __restrict__ inc_cnt,
                            int* __restrict__ out_cnt, const int* __restrict__ n_ptr, int B)
{
    const int N = n_ptr[0];
    const int stride = gridDim.x * blockDim.x;
    for (int i = blockIdx.x * blockDim.x + threadIdx.x; i < N; i += stride)
        table[i] = -1;
    for (int i = blockIdx.x * blockDim.x + threadIdx.x; i < B; i += stride) {
        inc_cnt[i] = 0;
        out_cnt[i] = 0;
    }
}

// ---- Kernel A1: build node -> batch-index chains (handles duplicate entities) ----
__global__ void chain_kernel(const int* __restrict__ entity_index, int* __restrict__ table,
                             int* __restrict__ next, const int* __restrict__ n_ptr, int B)
{
    const int N = n_ptr[0];
    const int b = blockIdx.x * blockDim.x + threadIdx.x;
    if (b >= B) return;
    const int e = entity_index[b];
    if (e < 0 || e >= N) { next[b] = -1; return; }  // invalid entity: not in table
    next[b] = atomicExch(&table[e], b);
}

// ---- Kernel B: single edge-centric scan ----
__global__ __launch_bounds__(256) void scan_kernel(
    const int*   __restrict__ edge_src,
    const int*   __restrict__ edge_dst,
    const float* __restrict__ edge_times,
    const int*   __restrict__ table,
    const int*   __restrict__ next,
    int* __restrict__ inc_cnt, int* __restrict__ out_cnt,
    unsigned long long* __restrict__ inc_key,
    unsigned long long* __restrict__ out_key,
    int E)
{
    const int stride = gridDim.x * blockDim.x;
    const int nvec   = E >> 2;
    const int4* src4 = (const int4*)edge_src;
    const int4* dst4 = (const int4*)edge_dst;

    for (int v = blockIdx.x * blockDim.x + threadIdx.x; v < nvec; v += stride) {
        const int4 s4 = src4[v];
        const int4 d4 = dst4[v];
        const int base = v << 2;
        const int ss[4] = { s4.x, s4.y, s4.z, s4.w };
        const int dd[4] = { d4.x, d4.y, d4.z, d4.w };
        #pragma unroll
        for (int j = 0; j < 4; ++j) {
            const int i = base + j;
            int bb = table[dd[j]];           // incoming: dst == entity
            if (bb != -1) {
                const unsigned long long key =
                    ((unsigned long long)__float_as_uint(edge_times[i]) << 32)
                    | (unsigned long long)(0xFFFFFFFFu - (unsigned)i);
                do {
                    const int p = atomicAdd(&inc_cnt[bb], 1);
                    if (p < CAP) inc_key[(size_t)bb * CAP + p] = key;
                    bb = next[bb];
                } while (bb != -1);
            }
            bb = table[ss[j]];               // outgoing: src == entity
            if (bb != -1) {
                const unsigned long long key =
                    ((unsigned long long)__float_as_uint(edge_times[i]) << 32)
                    | (unsigned long long)(0xFFFFFFFFu - (unsigned)i);
                do {
                    const int p = atomicAdd(&out_cnt[bb], 1);
                    if (p < CAP) out_key[(size_t)bb * CAP + p] = key;
                    bb = next[bb];
                } while (bb != -1);
            }
        }
    }
    // tail (E % 4)
    for (int i = (nvec << 2) + blockIdx.x * blockDim.x + threadIdx.x; i < E; i += stride) {
        const int s = edge_src[i], d = edge_dst[i];
        const unsigned long long key =
            ((unsigned long long)__float_as_uint(edge_times[i]) << 32)
            | (unsigned long long)(0xFFFFFFFFu - (unsigned)i);
        int bb = table[d];
        while (bb != -1) {
            const int p = atomicAdd(&inc_cnt[bb], 1);
            if (p < CAP) inc_key[(size_t)bb * CAP + p] = key;
            bb = next[bb];
        }
        bb = table[s];
        while (bb != -1) {
            const int p = atomicAdd(&out_cnt[bb], 1);
            if (p < CAP) out_key[(size_t)bb * CAP + p] = key;
            bb = next[bb];
        }
    }
}

// ---- Kernel C: per-batch top-k selection + masked-mean aggregate ----
__global__ __launch_bounds__(128) void agg_kernel(
    const int*   __restrict__ edge_types,
    const float* __restrict__ qw,
    const int*   __restrict__ inc_cnt, const int* __restrict__ out_cnt,
    const unsigned long long* __restrict__ inc_key,
    const unsigned long long* __restrict__ out_key,
    const int*   __restrict__ k_ptr,
    float*       __restrict__ out,
    int D)
{
    const int b    = blockIdx.x;
    const int tid  = threadIdx.x;
    const int nthr = blockDim.x;
    const int k    = k_ptr[0];
    const int kh   = k >> 1;

    __shared__ unsigned long long s_inc[CAP];
    __shared__ unsigned long long s_out[CAP];
    __shared__ int s_sel[2 * MAXK];

    const int full_in  = inc_cnt[b];
    const int full_out = out_cnt[b];
    const int c_in  = min(full_in,  CAP);
    const int c_out = min(full_out, CAP);

    const int inc_take  = min(kh, full_in);
    const int remaining = (inc_take > 0) ? (k - inc_take) : k;
    const int out_take  = min(remaining, full_out);

    for (int j = tid; j < c_in;  j += nthr) s_inc[j] = inc_key[(size_t)b * CAP + j];
    for (int j = tid; j < c_out; j += nthr) s_out[j] = out_key[(size_t)b * CAP + j];
    __syncthreads();

    // rank-based top-k (keys are unique: edge index embedded)
    for (int j = tid; j < c_in; j += nthr) {
        const unsigned long long kj = s_inc[j];
        int rank = 0;
        for (int m = 0; m < c_in; ++m) rank += (s_inc[m] > kj);
        if (rank < inc_take) {
            const int idx = (int)(0xFFFFFFFFu - (unsigned)(kj & 0xFFFFFFFFull));
            s_sel[rank] = edge_types[idx];
        }
    }
    for (int j = tid; j < c_out; j += nthr) {
        const unsigned long long kj = s_out[j];
        int rank = 0;
        for (int m = 0; m < c_out; ++m) rank += (s_out[m] > kj);
        if (rank < out_take) {
            const int idx = (int)(0xFFFFFFFFu - (unsigned)(kj & 0xFFFFFFFFull));
            s_sel[MAXK + rank] = edge_types[idx];
        }
    }
    __syncthreads();

    const int cnt = inc_take + out_take;
    const float inv = 1.0f / (float)max(cnt, 1);
    for (int d = tid; d < D; d += nthr) {
        float acc = 0.0f;
        for (int s = 0; s < inc_take; ++s) acc += qw[s_sel[s] * D + d];
        for (int s = 0; s < out_take; ++s) acc += qw[s_sel[MAXK + s] * D + d];
        out[(size_t)b * D + d] = acc * inv;
    }
}

extern "C" void kernel_launch(void* const* d_in, const int* in_sizes, int n_in,
                              void* d_out, int out_size, void* d_ws, size_t ws_size,
                              hipStream_t stream)
{
    const int*   entity_index = (const int*)d_in[0];
    const int*   edge_src     = (const int*)d_in[1];
    const int*   edge_dst     = (const int*)d_in[2];
    const int*   edge_types   = (const int*)d_in[3];
    const float* edge_times   = (const float*)d_in[4];
    const float* qw           = (const float*)d_in[5];
    const int*   k_ptr        = (const int*)d_in[6];
    const int*   n_ptr        = (const int*)d_in[7];
    float*       out          = (float*)d_out;

    const int B = in_sizes[0];
    const int E = in_sizes[1];
    const int D = out_size / B;

    // Workspace layout (8-byte-aligned arrays first; table takes the rest):
    char* ws = (char*)d_ws;
    size_t off = 0;
    unsigned long long* inc_key = (unsigned long long*)(ws + off); off += (size_t)B * CAP * 8;
    unsigned long long* out_key = (unsigned long long*)(ws + off); off += (size_t)B * CAP * 8;
    int* inc_cnt = (int*)(ws + off); off += (size_t)B * 4;
    int* out_cnt = (int*)(ws + off); off += (size_t)B * 4;
    int* next    = (int*)(ws + off); off += (size_t)B * 4;
    int* table   = (int*)(ws + off);   // N ints, N read on device

    // A0: init (grid-stride; covers any N)
    hipLaunchKernelGGL(init_kernel, dim3(256), dim3(256), 0, stream,
                       table, inc_cnt, out_cnt, n_ptr, B);
    // A1: build chains
    hipLaunchKernelGGL(chain_kernel, dim3((B + 255) / 256), dim3(256), 0, stream,
                       entity_index, table, next, n_ptr, B);
    // B: edge scan
    hipLaunchKernelGGL(scan_kernel, dim3(256), dim3(256), 0, stream,
                       edge_src, edge_dst, edge_times, table, next,
                       inc_cnt, out_cnt, inc_key, out_key, E);
    // C: select + aggregate
    hipLaunchKernelGGL(agg_kernel, dim3(B), dim3(128), 0, stream,
                       edge_types, qw, inc_cnt, out_cnt, inc_key, out_key,
                       k_ptr, out, D);
}